// Round 9
// baseline (3467.246 us; speedup 1.0000x reference)
//
#include <hip/hip_runtime.h>
#include <math.h>

// Problem constants: B=4, H=384, W=1280, NUM=8, IDX_REF=4
static constexpr int B_ = 4;
static constexpr int H_ = 384;
static constexpr int W_ = 1280;
static constexpr int HW_ = H_ * W_;

// ---------------------------------------------------------------------------
// Guidance band = [normal(3), left(3), right(3), warp(right)-left(3)]
// layout (g, 12, rows, W) covering global rows [y0g, y0g+rows)
// ---------------------------------------------------------------------------
__global__ __launch_bounds__(256) void guidance_band(
    const float* __restrict__ disp, const float* __restrict__ normal,
    const float* __restrict__ left, const float* __restrict__ right,
    float* __restrict__ guid, int b0, int g, int y0g, int rows)
{
  int idx = blockIdx.x * 256 + threadIdx.x;
  if (idx >= g * rows * W_) return;
  int x = idx % W_;
  int t = idx / W_;
  int yr = t % rows;
  int gi = t / rows;
  int y = y0g + yr;
  int b = b0 + gi;
  int p = y * W_ + x;

  float d = disp[(size_t)b * HW_ + p];
  float xs = (float)x - d;
  float x0f = floorf(xs);
  int x0 = (int)x0f;
  float w1 = xs - x0f;
  int xi0 = x0, xi1 = x0 + 1;
  float v0 = (xi0 >= 0 && xi0 < W_) ? 1.f : 0.f;
  float v1 = (xi1 >= 0 && xi1 < W_) ? 1.f : 0.f;
  int xc0 = min(max(xi0, 0), W_ - 1);
  int xc1 = min(max(xi1, 0), W_ - 1);
  float w0f = (1.f - w1) * v0;
  float w1f = w1 * v1;

#pragma unroll
  for (int c = 0; c < 3; c++) {
    const float* rrow = right + (size_t)(b * 3 + c) * HW_ + (size_t)y * W_;
    float l = left[(size_t)(b * 3 + c) * HW_ + p];
    float n = normal[(size_t)(b * 3 + c) * HW_ + p];
    float r = rrow[x];
    float warped = w0f * rrow[xc0] + w1f * rrow[xc1];
    size_t base = ((size_t)gi * 12) * rows * W_ + (size_t)yr * W_ + x;
    size_t cs = (size_t)rows * W_;
    guid[base + (size_t)c * cs]       = n;
    guid[base + (size_t)(3 + c) * cs] = l;
    guid[base + (size_t)(6 + c) * cs] = r;
    guid[base + (size_t)(9 + c) * cs] = warped - l;
  }
}

// ---------------------------------------------------------------------------
// Weight repack: [co][ci][3][3] -> [co_block][ci][co_in_block(8)][12]
// (nonet padded 9->12 floats = 48B so every nonet is 16B-aligned and all 8
// nonets of a (co_block, ci) sit in one 384B run -> 2x float4 + 1x float
// loads from a single uniform base with immediate offsets; no per-load
// address VALU. Values unchanged -> conv numerics bit-identical.)
// ---------------------------------------------------------------------------
template <int C_IN, int NCO>
__global__ __launch_bounds__(256) void repack_w(
    const float* __restrict__ w, float* __restrict__ p)
{
  int i = blockIdx.x * 256 + threadIdx.x;
  constexpr int total = NCO * C_IN * 8 * 12;
  if (i >= total) return;
  int t = i % 12; int r = i / 12;
  int j = r % 8;  r /= 8;
  int ci = r % C_IN;
  int coi = r / C_IN;
  float v = 0.f;
  if (t < 9) v = w[((size_t)(coi * 8 + j) * C_IN + ci) * 9 + t];
  p[i] = v;
}

// ---------------------------------------------------------------------------
// Banded 3x3 conv, 2x2 pixels per thread, 32x32 tile / 256 threads,
// 8 output channels per block (32 named accumulators). CHUNK=4: LDS 19.6 KB
// -> 8 blocks/CU (R8: occupancy 70%, VALUBusy 77%). R9 change: packed
// weights (see repack_w) -> 3 vector loads per nonet, zero address VALU
// (R8 analysis: 72 per-lane weight loads + addressing were the residual
// ~0.6 issue-slots/FMA). Accumulation order unchanged -> bit-identical.
// Grid: (W/32) * ceil(out_rows/32) * (C_OUT/8) * g.
// ---------------------------------------------------------------------------
#define CONV_CO4(CO, A00, A01, A10, A11)                                       \
  {                                                                            \
    const float4 q0 = *(const float4*)(wbase + (CO) * 12);                     \
    const float4 q1 = *(const float4*)(wbase + (CO) * 12 + 4);                 \
    const float  w8 = wbase[(CO) * 12 + 8];                                    \
    const float w0 = q0.x, w1 = q0.y, w2 = q0.z, w3 = q0.w;                    \
    const float w4 = q1.x, w5 = q1.y, w6 = q1.z, w7 = q1.w;                    \
    A00 = fmaf(i00, w0, A00); A00 = fmaf(i01, w1, A00); A00 = fmaf(i02, w2, A00); \
    A00 = fmaf(i10, w3, A00); A00 = fmaf(i11, w4, A00); A00 = fmaf(i12, w5, A00); \
    A00 = fmaf(i20, w6, A00); A00 = fmaf(i21, w7, A00); A00 = fmaf(i22, w8, A00); \
    A01 = fmaf(i01, w0, A01); A01 = fmaf(i02, w1, A01); A01 = fmaf(i03, w2, A01); \
    A01 = fmaf(i11, w3, A01); A01 = fmaf(i12, w4, A01); A01 = fmaf(i13, w5, A01); \
    A01 = fmaf(i21, w6, A01); A01 = fmaf(i22, w7, A01); A01 = fmaf(i23, w8, A01); \
    A10 = fmaf(i10, w0, A10); A10 = fmaf(i11, w1, A10); A10 = fmaf(i12, w2, A10); \
    A10 = fmaf(i20, w3, A10); A10 = fmaf(i21, w4, A10); A10 = fmaf(i22, w5, A10); \
    A10 = fmaf(i30, w6, A10); A10 = fmaf(i31, w7, A10); A10 = fmaf(i32, w8, A10); \
    A11 = fmaf(i11, w0, A11); A11 = fmaf(i12, w1, A11); A11 = fmaf(i13, w2, A11); \
    A11 = fmaf(i21, w3, A11); A11 = fmaf(i22, w4, A11); A11 = fmaf(i23, w5, A11); \
    A11 = fmaf(i31, w6, A11); A11 = fmaf(i32, w7, A11); A11 = fmaf(i33, w8, A11); \
  }

template <int C_IN, int C_OUT, int CHUNK, bool BNRELU>
__global__ __launch_bounds__(256, 8) void conv3x3_px4(
    const float* __restrict__ in, const float* __restrict__ wpk,
    const float* __restrict__ bn_g, const float* __restrict__ bn_b,
    const float* __restrict__ bn_m, const float* __restrict__ bn_v,
    float* __restrict__ out,
    int in_y0, int in_rows, int out_y0, int out_rows)
{
  constexpr int TX = 32, TY = 32;
  static_assert(C_IN % CHUNK == 0, "chunking");
  static_assert(C_OUT % 8 == 0, "co tiling");
  constexpr int NCO = C_OUT / 8;
  constexpr int LH = TY + 2;      // 34
  constexpr int LWS = 36;         // 34 used + 2 pad; 16B-aligned rows
  constexpr int QPC = LH * 9;     // 306 quads per channel tile

  __shared__ float smem[CHUNK][LH][LWS];

  const int tilesX = W_ / TX;     // 40
  const int tilesY = (out_rows + TY - 1) / TY;
  int t = blockIdx.x;
  int txi = t % tilesX; t /= tilesX;
  int tyi = t % tilesY; t /= tilesY;
  int coi = t % NCO;
  int gi  = t / NCO;
  const int x0  = txi * TX;
  const int oy0 = out_y0 + tyi * TY;
  const int co0 = coi * 8;

  const int tid = threadIdx.x;
  const int lx2 = (tid & 15) * 2;   // cols lx2, lx2+1
  const int ly2 = (tid >> 4) * 2;   // rows ly2, ly2+1

  float a0_00 = 0.f, a0_01 = 0.f, a0_10 = 0.f, a0_11 = 0.f;
  float a1_00 = 0.f, a1_01 = 0.f, a1_10 = 0.f, a1_11 = 0.f;
  float a2_00 = 0.f, a2_01 = 0.f, a2_10 = 0.f, a2_11 = 0.f;
  float a3_00 = 0.f, a3_01 = 0.f, a3_10 = 0.f, a3_11 = 0.f;
  float a4_00 = 0.f, a4_01 = 0.f, a4_10 = 0.f, a4_11 = 0.f;
  float a5_00 = 0.f, a5_01 = 0.f, a5_10 = 0.f, a5_11 = 0.f;
  float a6_00 = 0.f, a6_01 = 0.f, a6_10 = 0.f, a6_11 = 0.f;
  float a7_00 = 0.f, a7_01 = 0.f, a7_10 = 0.f, a7_11 = 0.f;

  for (int c0 = 0; c0 < C_IN; c0 += CHUNK) {
    // ---- quad-vectorized staging ----
    for (int i = tid; i < CHUNK * QPC; i += 256) {
      int c  = i / QPC;
      int r  = i - c * QPC;
      int yy = r / 9;
      int q  = r - yy * 9;
      int gy = oy0 + yy - 1;
      int by = gy - in_y0;
      int gx = x0 + 4 * q - 1;
      float v0 = 0.f, v1 = 0.f, v2 = 0.f, v3 = 0.f;
      if ((unsigned)by < (unsigned)in_rows) {
        const float* src = in + ((size_t)(gi * C_IN + c0 + c) * in_rows + by) * W_;
        v0 = ((unsigned)(gx + 0) < (unsigned)W_) ? src[gx + 0] : 0.f;
        v1 = ((unsigned)(gx + 1) < (unsigned)W_) ? src[gx + 1] : 0.f;
        v2 = ((unsigned)(gx + 2) < (unsigned)W_) ? src[gx + 2] : 0.f;
        v3 = ((unsigned)(gx + 3) < (unsigned)W_) ? src[gx + 3] : 0.f;
      }
      float* dst = &smem[c][yy][4 * q];
      dst[0] = v0; dst[1] = v1; dst[2] = v2; dst[3] = v3;
    }
    __syncthreads();

    // uniform packed-weight base for this (co_block, c0) run
    const float* wbase = wpk + (size_t)(coi * C_IN + c0) * 96;

    for (int c = 0; c < CHUNK; c++) {
      const float* r0p = &smem[c][ly2 + 0][lx2];
      const float* r1p = &smem[c][ly2 + 1][lx2];
      const float* r2p = &smem[c][ly2 + 2][lx2];
      const float* r3p = &smem[c][ly2 + 3][lx2];
      float2 p00 = *(const float2*)(r0p), p01 = *(const float2*)(r0p + 2);
      float2 p10 = *(const float2*)(r1p), p11 = *(const float2*)(r1p + 2);
      float2 p20 = *(const float2*)(r2p), p21 = *(const float2*)(r2p + 2);
      float2 p30 = *(const float2*)(r3p), p31 = *(const float2*)(r3p + 2);
      float i00 = p00.x, i01 = p00.y, i02 = p01.x, i03 = p01.y;
      float i10 = p10.x, i11 = p10.y, i12 = p11.x, i13 = p11.y;
      float i20 = p20.x, i21 = p20.y, i22 = p21.x, i23 = p21.y;
      float i30 = p30.x, i31 = p30.y, i32 = p31.x, i33 = p31.y;
      CONV_CO4(0, a0_00, a0_01, a0_10, a0_11)
      CONV_CO4(1, a1_00, a1_01, a1_10, a1_11)
      CONV_CO4(2, a2_00, a2_01, a2_10, a2_11)
      CONV_CO4(3, a3_00, a3_01, a3_10, a3_11)
      CONV_CO4(4, a4_00, a4_01, a4_10, a4_11)
      CONV_CO4(5, a5_00, a5_01, a5_10, a5_11)
      CONV_CO4(6, a6_00, a6_01, a6_10, a6_11)
      CONV_CO4(7, a7_00, a7_01, a7_10, a7_11)
      wbase += 96;
    }
    __syncthreads();
  }

  const int oyA = oy0 + ly2;
  const int oyB = oyA + 1;
  const int ox  = x0 + lx2;
  const bool okA = (oyA < out_y0 + out_rows);
  const bool okB = (oyB < out_y0 + out_rows);

  float acc[8][4] = {
    {a0_00, a0_01, a0_10, a0_11}, {a1_00, a1_01, a1_10, a1_11},
    {a2_00, a2_01, a2_10, a2_11}, {a3_00, a3_01, a3_10, a3_11},
    {a4_00, a4_01, a4_10, a4_11}, {a5_00, a5_01, a5_10, a5_11},
    {a6_00, a6_01, a6_10, a6_11}, {a7_00, a7_01, a7_10, a7_11}};
#pragma unroll
  for (int j = 0; j < 8; j++) {
    float r00 = acc[j][0], r01 = acc[j][1], r10 = acc[j][2], r11 = acc[j][3];
    const int co = co0 + j;
    if constexpr (BNRELU) {
      float s = bn_g[co] * rsqrtf(bn_v[co] + 1e-5f);
      float o = bn_b[co] - bn_m[co] * s;
      r00 = fmaxf(r00 * s + o, 0.f);
      r01 = fmaxf(r01 * s + o, 0.f);
      r10 = fmaxf(r10 * s + o, 0.f);
      r11 = fmaxf(r11 * s + o, 0.f);
    }
    float* base = out + ((size_t)(gi * C_OUT + co) * out_rows) * W_;
    if (okA) { float2 v = {r00, r01}; *(float2*)&base[(size_t)(oyA - out_y0) * W_ + ox] = v; }
    if (okB) { float2 v = {r10, r11}; *(float2*)&base[(size_t)(oyB - out_y0) * W_ + ox] = v; }
  }
}

// ---------------------------------------------------------------------------
// Fused propagation epilogue over a band.
// oa layout (g, 24, rows, W): [o1(8)=dy, o2(8)=dx, aff_raw(8)]
// ---------------------------------------------------------------------------
__device__ __forceinline__ float bilin1(const float* __restrict__ img,
                                        float ys, float xs)
{
  float y0f = floorf(ys), x0f = floorf(xs);
  int y0 = (int)y0f, x0 = (int)x0f;
  float wy1 = ys - y0f, wx1 = xs - x0f;
  float wy0 = 1.f - wy1, wx0 = 1.f - wx1;
  int y1 = y0 + 1, x1 = x0 + 1;
  float vy0 = (y0 >= 0 && y0 < H_) ? 1.f : 0.f;
  float vy1 = (y1 >= 0 && y1 < H_) ? 1.f : 0.f;
  float vx0 = (x0 >= 0 && x0 < W_) ? 1.f : 0.f;
  float vx1 = (x1 >= 0 && x1 < W_) ? 1.f : 0.f;
  int yc0 = min(max(y0, 0), H_ - 1), yc1 = min(max(y1, 0), H_ - 1);
  int xc0 = min(max(x0, 0), W_ - 1), xc1 = min(max(x1, 0), W_ - 1);
  const float* r0 = img + (size_t)yc0 * W_;
  const float* r1 = img + (size_t)yc1 * W_;
  float v00 = r0[xc0], v01 = r0[xc1], v10 = r1[xc0], v11 = r1[xc1];
  return (wy0 * vy0) * ((wx0 * vx0) * v00 + (wx1 * vx1) * v01) +
         (wy1 * vy1) * ((wx0 * vx0) * v10 + (wx1 * vx1) * v11);
}

__global__ __launch_bounds__(256) void final_band(
    const float* __restrict__ oa, const float* __restrict__ conf,
    const float* __restrict__ disp, const float* __restrict__ asc,
    float* __restrict__ out, int b0, int g, int y0g, int rows)
{
  int idx = blockIdx.x * 256 + threadIdx.x;
  if (idx >= g * rows * W_) return;
  int x = idx % W_;
  int t = idx / W_;
  int yr = t % rows;
  int gi = t / rows;
  int y = y0g + yr;
  int b = b0 + gi;
  int p = y * W_ + x;

  const float scale = 1.f / (asc[0] + 1e-8f);
  const float* cimg = conf + (size_t)b * HW_;
  const float* dimg = disp + (size_t)b * HW_;
  const float* oab = oa + (size_t)gi * 24 * rows * W_;
  const size_t cs = (size_t)rows * W_;
  const size_t q = (size_t)yr * W_ + x;

  float offy[8], offx[8], a[8];
#pragma unroll
  for (int k = 0; k < 8; k++) {
    offy[k] = oab[(size_t)k * cs + q];
    offx[k] = oab[(size_t)(8 + k) * cs + q];
    float ar = oab[(size_t)(16 + k) * cs + q];
    float ca = bilin1(cimg, (float)y + offy[k], (float)x + offx[k]);
    a[k] = tanhf(ar) * scale * ca;
  }

  float s = 1e-4f;
#pragma unroll
  for (int k = 0; k < 8; k++) s += fabsf(a[k]);
  s = fmaxf(s, 1.f);
  float inv = 1.f / s;
  float suma = 0.f;
#pragma unroll
  for (int k = 0; k < 8; k++) { a[k] *= inv; suma += a[k]; }
  float aref = 1.f - suma;

  float inter = 0.f;
#pragma unroll
  for (int k9 = 0; k9 < 9; k9++) {
    float oy, ox, w;
    if (k9 < 4)       { oy = offy[k9];     ox = offx[k9];     w = a[k9]; }
    else if (k9 == 4) { oy = 0.f;          ox = 0.f;          w = aref;  }
    else              { oy = offy[k9 - 1]; ox = offx[k9 - 1]; w = a[k9 - 1]; }
    float ky = (float)(k9 / 3) - 1.f;
    float kx = (float)(k9 % 3) - 1.f;
    inter += w * bilin1(dimg, (float)y + ky + oy, (float)x + kx + ox);
  }
  inter = fmaxf(inter, 0.f);
  float cd = dimg[p];
  out[(size_t)b * HW_ + p] = fmaxf(0.7f * cd + 0.3f * inter, 0.f);
}

// ---------------------------------------------------------------------------
extern "C" void kernel_launch(void* const* d_in, const int* in_sizes, int n_in,
                              void* d_out, int out_size, void* d_ws, size_t ws_size,
                              hipStream_t stream)
{
  const float* disp   = (const float*)d_in[0];
  const float* normal = (const float*)d_in[1];
  const float* left   = (const float*)d_in[2];
  const float* right  = (const float*)d_in[3];
  const float* conf   = (const float*)d_in[4];
  const float* w1     = (const float*)d_in[5];
  const float* g1     = (const float*)d_in[6];
  const float* b1     = (const float*)d_in[7];
  const float* m1     = (const float*)d_in[8];
  const float* v1     = (const float*)d_in[9];
  const float* w2     = (const float*)d_in[10];
  const float* g2     = (const float*)d_in[11];
  const float* b2     = (const float*)d_in[12];
  const float* m2     = (const float*)d_in[13];
  const float* v2     = (const float*)d_in[14];
  const float* w3     = (const float*)d_in[15];
  const float* asc    = (const float*)d_in[16];
  float* out = (float*)d_out;

  // Packed weight sizes (floats): [NCO][C_IN][8][12]
  constexpr int W1P = 4 * 12 * 8 * 12;   //  4608
  constexpr int W2P = 8 * 32 * 8 * 12;   // 24576
  constexpr int W3P = 3 * 64 * 8 * 12;   // 18432
  constexpr int WPK_TOTAL = W1P + W2P + W3P;

  // Band buffers: guid (12ch, bh+6), x1 (32ch, bh+4), x2 (64ch, bh+2),
  // packed weights appended. oa (24ch, bh) aliases ws start.
  struct Cfg { int g, bh; };
  const Cfg cfgs[] = {{4, 384}, {2, 384}, {1, 384}, {4, 96}, {2, 96},
                      {1, 96}, {1, 48}, {1, 24}, {1, 12}, {1, 8}, {1, 4}};
  int G = 1, BH = 4;
  for (const Cfg& c : cfgs) {
    size_t rows = (size_t)12 * (c.bh + 6) + (size_t)32 * (c.bh + 4) +
                  (size_t)64 * (c.bh + 2);
    size_t need = ((size_t)c.g * rows * W_ + WPK_TOTAL) * sizeof(float);
    if (need <= ws_size) { G = c.g; BH = c.bh; break; }
  }

  float* ws = (float*)d_ws;
  float* guid_buf = ws;
  float* x1_buf   = guid_buf + (size_t)G * 12 * (BH + 6) * W_;
  float* x2_buf   = x1_buf   + (size_t)G * 32 * (BH + 4) * W_;
  float* w1p      = x2_buf   + (size_t)G * 64 * (BH + 2) * W_;
  float* w2p      = w1p + W1P;
  float* w3p      = w2p + W2P;
  float* oa_buf   = ws;  // alias: guid+x1 dead once conv3 runs

  // one-shot weight repacks (same work every call; capture-safe)
  repack_w<12, 4><<<(W1P + 255) / 256, 256, 0, stream>>>(w1, w1p);
  repack_w<32, 8><<<(W2P + 255) / 256, 256, 0, stream>>>(w2, w2p);
  repack_w<64, 3><<<(W3P + 255) / 256, 256, 0, stream>>>(w3, w3p);

  const int tilesX = W_ / 32;  // 40

  for (int b0 = 0; b0 < B_; b0 += G) {
    for (int y0 = 0; y0 < H_; y0 += BH) {
      const int rows_out = min(BH, H_ - y0);
      const int y_x2_0 = max(y0 - 1, 0);
      const int y_x2_1 = min(y0 + rows_out + 1, H_);
      const int rows_x2 = y_x2_1 - y_x2_0;
      const int y_x1_0 = max(y0 - 2, 0);
      const int y_x1_1 = min(y0 + rows_out + 2, H_);
      const int rows_x1 = y_x1_1 - y_x1_0;
      const int y_g_0 = max(y0 - 3, 0);
      const int y_g_1 = min(y0 + rows_out + 3, H_);
      const int rows_g = y_g_1 - y_g_0;

      {
        int n = G * rows_g * W_;
        guidance_band<<<(n + 255) / 256, 256, 0, stream>>>(
            disp, normal, left, right, guid_buf, b0, G, y_g_0, rows_g);
      }
      {
        // 12 -> 32: NCO=4, CHUNK=4 (3 rounds)
        int grid = tilesX * ((rows_x1 + 31) / 32) * 4 * G;
        conv3x3_px4<12, 32, 4, true><<<grid, 256, 0, stream>>>(
            guid_buf, w1p, g1, b1, m1, v1, x1_buf,
            y_g_0, rows_g, y_x1_0, rows_x1);
      }
      {
        // 32 -> 64: NCO=8, CHUNK=4 (8 rounds)
        int grid = tilesX * ((rows_x2 + 31) / 32) * 8 * G;
        conv3x3_px4<32, 64, 4, true><<<grid, 256, 0, stream>>>(
            x1_buf, w2p, g2, b2, m2, v2, x2_buf,
            y_x1_0, rows_x1, y_x2_0, rows_x2);
      }
      {
        // 64 -> 24: NCO=3, CHUNK=4 (16 rounds)
        int grid = tilesX * ((rows_out + 31) / 32) * 3 * G;
        conv3x3_px4<64, 24, 4, false><<<grid, 256, 0, stream>>>(
            x2_buf, w3p, nullptr, nullptr, nullptr, nullptr, oa_buf,
            y_x2_0, rows_x2, y0, rows_out);
      }
      {
        int n = G * rows_out * W_;
        final_band<<<(n + 255) / 256, 256, 0, stream>>>(
            oa_buf, conf, disp, asc, out, b0, G, y0, rows_out);
      }
    }
  }
}

// Round 10
// 2096.129 us; speedup vs baseline: 1.6541x; 1.6541x over previous
//
#include <hip/hip_runtime.h>
#include <math.h>

// Problem constants: B=4, H=384, W=1280, NUM=8, IDX_REF=4
static constexpr int B_ = 4;
static constexpr int H_ = 384;
static constexpr int W_ = 1280;
static constexpr int HW_ = H_ * W_;

// ---------------------------------------------------------------------------
// Guidance band = [normal(3), left(3), right(3), warp(right)-left(3)]
// layout (g, 12, rows, W) covering global rows [y0g, y0g+rows)
// ---------------------------------------------------------------------------
__global__ __launch_bounds__(256) void guidance_band(
    const float* __restrict__ disp, const float* __restrict__ normal,
    const float* __restrict__ left, const float* __restrict__ right,
    float* __restrict__ guid, int b0, int g, int y0g, int rows)
{
  int idx = blockIdx.x * 256 + threadIdx.x;
  if (idx >= g * rows * W_) return;
  int x = idx % W_;
  int t = idx / W_;
  int yr = t % rows;
  int gi = t / rows;
  int y = y0g + yr;
  int b = b0 + gi;
  int p = y * W_ + x;

  float d = disp[(size_t)b * HW_ + p];
  float xs = (float)x - d;
  float x0f = floorf(xs);
  int x0 = (int)x0f;
  float w1 = xs - x0f;
  int xi0 = x0, xi1 = x0 + 1;
  float v0 = (xi0 >= 0 && xi0 < W_) ? 1.f : 0.f;
  float v1 = (xi1 >= 0 && xi1 < W_) ? 1.f : 0.f;
  int xc0 = min(max(xi0, 0), W_ - 1);
  int xc1 = min(max(xi1, 0), W_ - 1);
  float w0f = (1.f - w1) * v0;
  float w1f = w1 * v1;

#pragma unroll
  for (int c = 0; c < 3; c++) {
    const float* rrow = right + (size_t)(b * 3 + c) * HW_ + (size_t)y * W_;
    float l = left[(size_t)(b * 3 + c) * HW_ + p];
    float n = normal[(size_t)(b * 3 + c) * HW_ + p];
    float r = rrow[x];
    float warped = w0f * rrow[xc0] + w1f * rrow[xc1];
    size_t base = ((size_t)gi * 12) * rows * W_ + (size_t)yr * W_ + x;
    size_t cs = (size_t)rows * W_;
    guid[base + (size_t)c * cs]       = n;
    guid[base + (size_t)(3 + c) * cs] = l;
    guid[base + (size_t)(6 + c) * cs] = r;
    guid[base + (size_t)(9 + c) * cs] = warped - l;
  }
}

// ---------------------------------------------------------------------------
// Banded 3x3 conv, 2x2 pixels per thread. 32x32 output tile / 256 threads;
// each thread computes a 2x2 pixel quad x 8 output channels = 32 NAMED
// accumulators; the 4x4 window (16 named floats) feeds 36 FMAs per
// weight-nonet. CHUNK=4: LDS 19.6 KB -> 8 blocks/CU (R8: occupancy 70%).
// R10 change vs R8: grid decomposition puts coi (co-block) FASTEST so the
// NCO sibling blocks reading the SAME input tile dispatch back-to-back and
// hit the die-level L3 instead of refetching from HBM (R8 diagnosis: conv2
// was memory-bound at 812 MB/dispatch = 8x reread of the 63.5 MB x1 band;
// R9's packed-weights experiment regressed via write amplification and is
// fully reverted). Pure block reordering -> bit-identical numerics.
// Grid: NCO * (W/32) * ceil(out_rows/32) * g, coi fastest.
// ---------------------------------------------------------------------------
#define CONV_CO4(CO, A00, A01, A10, A11)                                       \
  {                                                                            \
    const float* wp = wgt + ((size_t)(co0 + (CO)) * C_IN + ci) * 9;            \
    float w0 = wp[0], w1 = wp[1], w2 = wp[2], w3 = wp[3], w4 = wp[4];          \
    float w5 = wp[5], w6 = wp[6], w7 = wp[7], w8 = wp[8];                      \
    A00 = fmaf(i00, w0, A00); A00 = fmaf(i01, w1, A00); A00 = fmaf(i02, w2, A00); \
    A00 = fmaf(i10, w3, A00); A00 = fmaf(i11, w4, A00); A00 = fmaf(i12, w5, A00); \
    A00 = fmaf(i20, w6, A00); A00 = fmaf(i21, w7, A00); A00 = fmaf(i22, w8, A00); \
    A01 = fmaf(i01, w0, A01); A01 = fmaf(i02, w1, A01); A01 = fmaf(i03, w2, A01); \
    A01 = fmaf(i11, w3, A01); A01 = fmaf(i12, w4, A01); A01 = fmaf(i13, w5, A01); \
    A01 = fmaf(i21, w6, A01); A01 = fmaf(i22, w7, A01); A01 = fmaf(i23, w8, A01); \
    A10 = fmaf(i10, w0, A10); A10 = fmaf(i11, w1, A10); A10 = fmaf(i12, w2, A10); \
    A10 = fmaf(i20, w3, A10); A10 = fmaf(i21, w4, A10); A10 = fmaf(i22, w5, A10); \
    A10 = fmaf(i30, w6, A10); A10 = fmaf(i31, w7, A10); A10 = fmaf(i32, w8, A10); \
    A11 = fmaf(i11, w0, A11); A11 = fmaf(i12, w1, A11); A11 = fmaf(i13, w2, A11); \
    A11 = fmaf(i21, w3, A11); A11 = fmaf(i22, w4, A11); A11 = fmaf(i23, w5, A11); \
    A11 = fmaf(i31, w6, A11); A11 = fmaf(i32, w7, A11); A11 = fmaf(i33, w8, A11); \
  }

template <int C_IN, int C_OUT, int CHUNK, bool BNRELU>
__global__ __launch_bounds__(256, 8) void conv3x3_px4(
    const float* __restrict__ in, const float* __restrict__ wgt,
    const float* __restrict__ bn_g, const float* __restrict__ bn_b,
    const float* __restrict__ bn_m, const float* __restrict__ bn_v,
    float* __restrict__ out,
    int in_y0, int in_rows, int out_y0, int out_rows)
{
  constexpr int TX = 32, TY = 32;
  static_assert(C_IN % CHUNK == 0, "chunking");
  static_assert(C_OUT % 8 == 0, "co tiling");
  constexpr int NCO = C_OUT / 8;
  constexpr int LH = TY + 2;      // 34
  constexpr int LWS = 36;         // 34 used + 2 pad; 16B-aligned rows
  constexpr int QPC = LH * 9;     // 306 quads per channel tile

  __shared__ float smem[CHUNK][LH][LWS];

  const int tilesX = W_ / TX;     // 40
  const int tilesY = (out_rows + TY - 1) / TY;
  int t = blockIdx.x;
  int coi = t % NCO;  t /= NCO;    // coi FASTEST: co-siblings share L3 tile
  int txi = t % tilesX; t /= tilesX;
  int tyi = t % tilesY;
  int gi  = t / tilesY;
  const int x0  = txi * TX;
  const int oy0 = out_y0 + tyi * TY;
  const int co0 = coi * 8;

  const int tid = threadIdx.x;
  const int lx2 = (tid & 15) * 2;   // cols lx2, lx2+1
  const int ly2 = (tid >> 4) * 2;   // rows ly2, ly2+1

  float a0_00 = 0.f, a0_01 = 0.f, a0_10 = 0.f, a0_11 = 0.f;
  float a1_00 = 0.f, a1_01 = 0.f, a1_10 = 0.f, a1_11 = 0.f;
  float a2_00 = 0.f, a2_01 = 0.f, a2_10 = 0.f, a2_11 = 0.f;
  float a3_00 = 0.f, a3_01 = 0.f, a3_10 = 0.f, a3_11 = 0.f;
  float a4_00 = 0.f, a4_01 = 0.f, a4_10 = 0.f, a4_11 = 0.f;
  float a5_00 = 0.f, a5_01 = 0.f, a5_10 = 0.f, a5_11 = 0.f;
  float a6_00 = 0.f, a6_01 = 0.f, a6_10 = 0.f, a6_11 = 0.f;
  float a7_00 = 0.f, a7_01 = 0.f, a7_10 = 0.f, a7_11 = 0.f;

  for (int c0 = 0; c0 < C_IN; c0 += CHUNK) {
    // ---- quad-vectorized staging ----
    for (int i = tid; i < CHUNK * QPC; i += 256) {
      int c  = i / QPC;
      int r  = i - c * QPC;
      int yy = r / 9;
      int q  = r - yy * 9;
      int gy = oy0 + yy - 1;
      int by = gy - in_y0;
      int gx = x0 + 4 * q - 1;
      float v0 = 0.f, v1 = 0.f, v2 = 0.f, v3 = 0.f;
      if ((unsigned)by < (unsigned)in_rows) {
        const float* src = in + ((size_t)(gi * C_IN + c0 + c) * in_rows + by) * W_;
        v0 = ((unsigned)(gx + 0) < (unsigned)W_) ? src[gx + 0] : 0.f;
        v1 = ((unsigned)(gx + 1) < (unsigned)W_) ? src[gx + 1] : 0.f;
        v2 = ((unsigned)(gx + 2) < (unsigned)W_) ? src[gx + 2] : 0.f;
        v3 = ((unsigned)(gx + 3) < (unsigned)W_) ? src[gx + 3] : 0.f;
      }
      float* dst = &smem[c][yy][4 * q];
      dst[0] = v0; dst[1] = v1; dst[2] = v2; dst[3] = v3;
    }
    __syncthreads();

    for (int c = 0; c < CHUNK; c++) {
      const float* r0p = &smem[c][ly2 + 0][lx2];
      const float* r1p = &smem[c][ly2 + 1][lx2];
      const float* r2p = &smem[c][ly2 + 2][lx2];
      const float* r3p = &smem[c][ly2 + 3][lx2];
      float2 p00 = *(const float2*)(r0p), p01 = *(const float2*)(r0p + 2);
      float2 p10 = *(const float2*)(r1p), p11 = *(const float2*)(r1p + 2);
      float2 p20 = *(const float2*)(r2p), p21 = *(const float2*)(r2p + 2);
      float2 p30 = *(const float2*)(r3p), p31 = *(const float2*)(r3p + 2);
      float i00 = p00.x, i01 = p00.y, i02 = p01.x, i03 = p01.y;
      float i10 = p10.x, i11 = p10.y, i12 = p11.x, i13 = p11.y;
      float i20 = p20.x, i21 = p20.y, i22 = p21.x, i23 = p21.y;
      float i30 = p30.x, i31 = p30.y, i32 = p31.x, i33 = p31.y;
      const int ci = c0 + c;
      CONV_CO4(0, a0_00, a0_01, a0_10, a0_11)
      CONV_CO4(1, a1_00, a1_01, a1_10, a1_11)
      CONV_CO4(2, a2_00, a2_01, a2_10, a2_11)
      CONV_CO4(3, a3_00, a3_01, a3_10, a3_11)
      CONV_CO4(4, a4_00, a4_01, a4_10, a4_11)
      CONV_CO4(5, a5_00, a5_01, a5_10, a5_11)
      CONV_CO4(6, a6_00, a6_01, a6_10, a6_11)
      CONV_CO4(7, a7_00, a7_01, a7_10, a7_11)
    }
    __syncthreads();
  }

  const int oyA = oy0 + ly2;
  const int oyB = oyA + 1;
  const int ox  = x0 + lx2;
  const bool okA = (oyA < out_y0 + out_rows);
  const bool okB = (oyB < out_y0 + out_rows);

  float acc[8][4] = {
    {a0_00, a0_01, a0_10, a0_11}, {a1_00, a1_01, a1_10, a1_11},
    {a2_00, a2_01, a2_10, a2_11}, {a3_00, a3_01, a3_10, a3_11},
    {a4_00, a4_01, a4_10, a4_11}, {a5_00, a5_01, a5_10, a5_11},
    {a6_00, a6_01, a6_10, a6_11}, {a7_00, a7_01, a7_10, a7_11}};
#pragma unroll
  for (int j = 0; j < 8; j++) {
    float r00 = acc[j][0], r01 = acc[j][1], r10 = acc[j][2], r11 = acc[j][3];
    const int co = co0 + j;
    if constexpr (BNRELU) {
      float s = bn_g[co] * rsqrtf(bn_v[co] + 1e-5f);
      float o = bn_b[co] - bn_m[co] * s;
      r00 = fmaxf(r00 * s + o, 0.f);
      r01 = fmaxf(r01 * s + o, 0.f);
      r10 = fmaxf(r10 * s + o, 0.f);
      r11 = fmaxf(r11 * s + o, 0.f);
    }
    float* base = out + ((size_t)(gi * C_OUT + co) * out_rows) * W_;
    if (okA) { float2 v = {r00, r01}; *(float2*)&base[(size_t)(oyA - out_y0) * W_ + ox] = v; }
    if (okB) { float2 v = {r10, r11}; *(float2*)&base[(size_t)(oyB - out_y0) * W_ + ox] = v; }
  }
}

// ---------------------------------------------------------------------------
// Fused propagation epilogue over a band.
// oa layout (g, 24, rows, W): [o1(8)=dy, o2(8)=dx, aff_raw(8)]
// ---------------------------------------------------------------------------
__device__ __forceinline__ float bilin1(const float* __restrict__ img,
                                        float ys, float xs)
{
  float y0f = floorf(ys), x0f = floorf(xs);
  int y0 = (int)y0f, x0 = (int)x0f;
  float wy1 = ys - y0f, wx1 = xs - x0f;
  float wy0 = 1.f - wy1, wx0 = 1.f - wx1;
  int y1 = y0 + 1, x1 = x0 + 1;
  float vy0 = (y0 >= 0 && y0 < H_) ? 1.f : 0.f;
  float vy1 = (y1 >= 0 && y1 < H_) ? 1.f : 0.f;
  float vx0 = (x0 >= 0 && x0 < W_) ? 1.f : 0.f;
  float vx1 = (x1 >= 0 && x1 < W_) ? 1.f : 0.f;
  int yc0 = min(max(y0, 0), H_ - 1), yc1 = min(max(y1, 0), H_ - 1);
  int xc0 = min(max(x0, 0), W_ - 1), xc1 = min(max(x1, 0), W_ - 1);
  const float* r0 = img + (size_t)yc0 * W_;
  const float* r1 = img + (size_t)yc1 * W_;
  float v00 = r0[xc0], v01 = r0[xc1], v10 = r1[xc0], v11 = r1[xc1];
  return (wy0 * vy0) * ((wx0 * vx0) * v00 + (wx1 * vx1) * v01) +
         (wy1 * vy1) * ((wx0 * vx0) * v10 + (wx1 * vx1) * v11);
}

__global__ __launch_bounds__(256) void final_band(
    const float* __restrict__ oa, const float* __restrict__ conf,
    const float* __restrict__ disp, const float* __restrict__ asc,
    float* __restrict__ out, int b0, int g, int y0g, int rows)
{
  int idx = blockIdx.x * 256 + threadIdx.x;
  if (idx >= g * rows * W_) return;
  int x = idx % W_;
  int t = idx / W_;
  int yr = t % rows;
  int gi = t / rows;
  int y = y0g + yr;
  int b = b0 + gi;
  int p = y * W_ + x;

  const float scale = 1.f / (asc[0] + 1e-8f);
  const float* cimg = conf + (size_t)b * HW_;
  const float* dimg = disp + (size_t)b * HW_;
  const float* oab = oa + (size_t)gi * 24 * rows * W_;
  const size_t cs = (size_t)rows * W_;
  const size_t q = (size_t)yr * W_ + x;

  float offy[8], offx[8], a[8];
#pragma unroll
  for (int k = 0; k < 8; k++) {
    offy[k] = oab[(size_t)k * cs + q];
    offx[k] = oab[(size_t)(8 + k) * cs + q];
    float ar = oab[(size_t)(16 + k) * cs + q];
    float ca = bilin1(cimg, (float)y + offy[k], (float)x + offx[k]);
    a[k] = tanhf(ar) * scale * ca;
  }

  float s = 1e-4f;
#pragma unroll
  for (int k = 0; k < 8; k++) s += fabsf(a[k]);
  s = fmaxf(s, 1.f);
  float inv = 1.f / s;
  float suma = 0.f;
#pragma unroll
  for (int k = 0; k < 8; k++) { a[k] *= inv; suma += a[k]; }
  float aref = 1.f - suma;

  float inter = 0.f;
#pragma unroll
  for (int k9 = 0; k9 < 9; k9++) {
    float oy, ox, w;
    if (k9 < 4)       { oy = offy[k9];     ox = offx[k9];     w = a[k9]; }
    else if (k9 == 4) { oy = 0.f;          ox = 0.f;          w = aref;  }
    else              { oy = offy[k9 - 1]; ox = offx[k9 - 1]; w = a[k9 - 1]; }
    float ky = (float)(k9 / 3) - 1.f;
    float kx = (float)(k9 % 3) - 1.f;
    inter += w * bilin1(dimg, (float)y + ky + oy, (float)x + kx + ox);
  }
  inter = fmaxf(inter, 0.f);
  float cd = dimg[p];
  out[(size_t)b * HW_ + p] = fmaxf(0.7f * cd + 0.3f * inter, 0.f);
}

// ---------------------------------------------------------------------------
extern "C" void kernel_launch(void* const* d_in, const int* in_sizes, int n_in,
                              void* d_out, int out_size, void* d_ws, size_t ws_size,
                              hipStream_t stream)
{
  const float* disp   = (const float*)d_in[0];
  const float* normal = (const float*)d_in[1];
  const float* left   = (const float*)d_in[2];
  const float* right  = (const float*)d_in[3];
  const float* conf   = (const float*)d_in[4];
  const float* w1     = (const float*)d_in[5];
  const float* g1     = (const float*)d_in[6];
  const float* b1     = (const float*)d_in[7];
  const float* m1     = (const float*)d_in[8];
  const float* v1     = (const float*)d_in[9];
  const float* w2     = (const float*)d_in[10];
  const float* g2     = (const float*)d_in[11];
  const float* b2     = (const float*)d_in[12];
  const float* m2     = (const float*)d_in[13];
  const float* v2     = (const float*)d_in[14];
  const float* w3     = (const float*)d_in[15];
  const float* asc    = (const float*)d_in[16];
  float* out = (float*)d_out;

  // Band buffers: guid (12ch, bh+6), x1 (32ch, bh+4), x2 (64ch, bh+2).
  // oa (24ch, bh) aliases the ws start (guid+x1 dead by conv3).
  struct Cfg { int g, bh; };
  const Cfg cfgs[] = {{4, 384}, {2, 384}, {1, 384}, {4, 96}, {2, 96},
                      {1, 96}, {1, 48}, {1, 24}, {1, 12}, {1, 8}, {1, 4}};
  int G = 1, BH = 4;
  for (const Cfg& c : cfgs) {
    size_t rows = (size_t)12 * (c.bh + 6) + (size_t)32 * (c.bh + 4) +
                  (size_t)64 * (c.bh + 2);
    size_t need = (size_t)c.g * rows * W_ * sizeof(float);
    if (need <= ws_size) { G = c.g; BH = c.bh; break; }
  }

  float* ws = (float*)d_ws;
  float* guid_buf = ws;
  float* x1_buf   = guid_buf + (size_t)G * 12 * (BH + 6) * W_;
  float* x2_buf   = x1_buf   + (size_t)G * 32 * (BH + 4) * W_;
  float* oa_buf   = ws;  // alias: guid+x1 dead once conv3 runs

  const int tilesX = W_ / 32;  // 40

  for (int b0 = 0; b0 < B_; b0 += G) {
    for (int y0 = 0; y0 < H_; y0 += BH) {
      const int rows_out = min(BH, H_ - y0);
      const int y_x2_0 = max(y0 - 1, 0);
      const int y_x2_1 = min(y0 + rows_out + 1, H_);
      const int rows_x2 = y_x2_1 - y_x2_0;
      const int y_x1_0 = max(y0 - 2, 0);
      const int y_x1_1 = min(y0 + rows_out + 2, H_);
      const int rows_x1 = y_x1_1 - y_x1_0;
      const int y_g_0 = max(y0 - 3, 0);
      const int y_g_1 = min(y0 + rows_out + 3, H_);
      const int rows_g = y_g_1 - y_g_0;

      {
        int n = G * rows_g * W_;
        guidance_band<<<(n + 255) / 256, 256, 0, stream>>>(
            disp, normal, left, right, guid_buf, b0, G, y_g_0, rows_g);
      }
      {
        // 12 -> 32: NCO=4, CHUNK=4 (3 rounds)
        int grid = 4 * tilesX * ((rows_x1 + 31) / 32) * G;
        conv3x3_px4<12, 32, 4, true><<<grid, 256, 0, stream>>>(
            guid_buf, w1, g1, b1, m1, v1, x1_buf,
            y_g_0, rows_g, y_x1_0, rows_x1);
      }
      {
        // 32 -> 64: NCO=8, CHUNK=4 (8 rounds)
        int grid = 8 * tilesX * ((rows_x2 + 31) / 32) * G;
        conv3x3_px4<32, 64, 4, true><<<grid, 256, 0, stream>>>(
            x1_buf, w2, g2, b2, m2, v2, x2_buf,
            y_x1_0, rows_x1, y_x2_0, rows_x2);
      }
      {
        // 64 -> 24: NCO=3, CHUNK=4 (16 rounds)
        int grid = 3 * tilesX * ((rows_out + 31) / 32) * G;
        conv3x3_px4<64, 24, 4, false><<<grid, 256, 0, stream>>>(
            x2_buf, w3, nullptr, nullptr, nullptr, nullptr, oa_buf,
            y_x2_0, rows_x2, y0, rows_out);
      }
      {
        int n = G * rows_out * W_;
        final_band<<<(n + 255) / 256, 256, 0, stream>>>(
            oa_buf, conf, disp, asc, out, b0, G, y0, rows_out);
      }
    }
  }
}